// Round 19
// baseline (98.241 us; speedup 1.0000x reference)
//
#include <hip/hip_runtime.h>
#include <hip/hip_bf16.h>
#include <math.h>

#define S_LEN 2048
#define C_DIM 512
#define NH 16
#define HD 32
#define PLANE_U (NH * S_LEN * HD)   // 1,048,576 ushorts = 2MB per plane
#define WPL 262144                  // 512*512 ushorts per W plane

typedef __attribute__((ext_vector_type(8)))  short bf16x8;
typedef __attribute__((ext_vector_type(4)))  float f32x4;
typedef __attribute__((ext_vector_type(16))) float f32x16;
typedef __attribute__((ext_vector_type(4)))  unsigned int u32x4;

#if __has_builtin(__builtin_amdgcn_exp2f)
#define EXP2(x) __builtin_amdgcn_exp2f(x)
#else
#define EXP2(x) exp2f(x)
#endif

// pack 2 floats -> 2 bf16 in one dword via v_cvt_pk_bf16_f32 (RNE); a = low
__device__ __forceinline__ unsigned int pk_bf16(float a, float b) {
    float2 f; f.x = a; f.y = b;
    __hip_bfloat162 t = __float22bfloat162_rn(f);
    return *reinterpret_cast<unsigned int*>(&t);
}

// ---------------- W pre-conversion: fp32 -> bf16 RNE planes ---------------
// WF (at ws + 6*PLANE_U): plane z*2+{0:re,1:im}, each [o:512][k:512] ushort.
__global__ __launch_bounds__(256)
void wcvt(const float* __restrict__ Wq, const float* __restrict__ Wk,
          const float* __restrict__ Wv, unsigned short* __restrict__ ws)
{
    const int tid = blockIdx.x*256 + threadIdx.x;   // 98304 total
    const int z   = tid >> 15;
    const int rem = tid & 32767;
    const int row = rem >> 6;
    const int kc  = (rem & 63) * 8;                 // 8 complex
    const float2* w2 = (const float2*)(z == 0 ? Wq : (z == 1 ? Wk : Wv));
    const float4* s4 = (const float4*)(w2 + (size_t)row*C_DIM + kc);
    float4 f0 = s4[0], f1 = s4[1], f2v = s4[2], f3 = s4[3];
    float re[8] = {f0.x,f0.z,f1.x,f1.z,f2v.x,f2v.z,f3.x,f3.z};
    float im[8] = {f0.y,f0.w,f1.y,f1.w,f2v.y,f2v.w,f3.y,f3.w};
    u32x4 rh, ih;
    #pragma unroll
    for (int p2 = 0; p2 < 4; ++p2) {
        rh[p2] = pk_bf16(re[2*p2], re[2*p2+1]);
        ih[p2] = pk_bf16(im[2*p2], im[2*p2+1]);
    }
    unsigned short* wf = ws + 6*(size_t)PLANE_U;
    const size_t off = (size_t)row*C_DIM + kc;
    *(u32x4*)&wf[(size_t)(z*2+0)*WPL + off] = rh;
    *(u32x4*)&wf[(size_t)(z*2+1)*WPL + off] = ih;
}

// ---------------- projection: complex GEMM, in-block split-K --------------
// D = W·X^T, hi-only RNE (4 mfma/tile/k-step). 512-thread blocks = 2 k-groups
// of 4 waves: group g reduces k in [g*256, g*256+256) with its own LDS tile;
// partials combined through LDS at the end (group 0 deposits, group 1 adds
// and runs the epilogue). 24 waves/CU resident vs 12 for the 256-thr version.
// z==0 (q): -> natural [h][s][d], PRE-SCALED by log2(e)/sqrt(32)
// z==1 (k): -> fragment-order KF[h][c][frag][lane][8], kappa pre-folded
// z==2 (v): -> fragment-order VF[h][c][frag][lane][8] (from D[o][s])
#define PROW2 72   // padded LDS row stride in ushorts (144B)

__global__ __launch_bounds__(512, 6)
void proj_mfma(const float* __restrict__ Q, const float* __restrict__ V,
               const float* __restrict__ K,
               const float* __restrict__ bq, const float* __restrict__ bk,
               const float* __restrict__ bv,
               unsigned short* __restrict__ ws)
{
    const int z = blockIdx.z;
    const float *X, *b;
    if (z == 0)      { X = Q; b = bq; }
    else if (z == 1) { X = K; b = bk; }
    else             { X = V; b = bv; }

    const int s0 = blockIdx.x * 64;
    const int o0 = blockIdx.y * 64;

    const float2* Bsrc = (const float2*)X;
    const unsigned short* wf = ws + 6*(size_t)PLANE_U;
    const size_t pb = (size_t)z*2*WPL;

    // [group][re/im][64 rows x PROW2] = 36,864B; aliased as 33,792B combine
    __shared__ __align__(16) unsigned short LB[2][2][64*PROW2];

    const int t    = threadIdx.x;
    const int grp  = t >> 8;        // k-half owner
    const int tg   = t & 255;
    const int wave = tg >> 6;       // 0..3 within group
    const int lr   = t & 15;
    const int g    = (t & 63) >> 4;
    const int srow = tg >> 2;       // B staging row 0..63
    const int skc  = (tg & 3) * 16; // B staging k chunk (16 complex)

    const f32x4 zf = {0.f,0.f,0.f,0.f};
    f32x4 accR[4], accI[4];
    #pragma unroll
    for (int i = 0; i < 4; ++i) { accR[i] = zf; accI[i] = zf; }

    const size_t arow = (size_t)(o0 + wave*16 + lr) * C_DIM;
    const int kbase = grp * 256;

    for (int it = 0; it < 4; ++it) {
        const int k0 = kbase + it*64;
        // ---- A fragments for both k-steps: direct bf16 loads (L2-hot) ----
        const size_t ak = arow + k0 + g*8;
        bf16x8 aRH0 = *(const bf16x8*)&wf[pb + ak];
        bf16x8 aRH1 = *(const bf16x8*)&wf[pb + ak + 32];
        bf16x8 aIH0 = *(const bf16x8*)&wf[pb + WPL + ak];
        bf16x8 aIH1 = *(const bf16x8*)&wf[pb + WPL + ak + 32];
        bf16x8 aIHn0, aIHn1;
        #pragma unroll
        for (int j = 0; j < 4; ++j) {
            ((unsigned int*)&aIHn0)[j] = ((const unsigned int*)&aIH0)[j] ^ 0x80008000u;
            ((unsigned int*)&aIHn1)[j] = ((const unsigned int*)&aIH1)[j] ^ 0x80008000u;
        }

        __syncthreads();   // previous tiles fully consumed (both groups)
        // ---- stage this group's B tile: 64 rows x 64 k (16 cplx/thr) ----
        {
            const float4* s4 = (const float4*)(Bsrc + (size_t)(s0 + srow)*C_DIM + k0 + skc);
            u32x4 rhA, ihA, rhB, ihB;
            #pragma unroll
            for (int p2 = 0; p2 < 4; ++p2) {
                float4 fa = s4[2*p2], fb = s4[2*p2+1];
                unsigned int rw = pk_bf16(fa.x, fa.z);
                unsigned int r2 = pk_bf16(fb.x, fb.z);
                unsigned int iw = pk_bf16(fa.y, fa.w);
                unsigned int i2 = pk_bf16(fb.y, fb.w);
                if (p2 < 2) { rhA[2*p2] = rw; rhA[2*p2+1] = r2; ihA[2*p2] = iw; ihA[2*p2+1] = i2; }
                else        { rhB[2*(p2-2)] = rw; rhB[2*(p2-2)+1] = r2; ihB[2*(p2-2)] = iw; ihB[2*(p2-2)+1] = i2; }
            }
            int wb = srow*PROW2 + skc;
            *(u32x4*)&LB[grp][0][wb]     = rhA;
            *(u32x4*)&LB[grp][0][wb + 8] = rhB;
            *(u32x4*)&LB[grp][1][wb]     = ihA;
            *(u32x4*)&LB[grp][1][wb + 8] = ihB;
        }
        __syncthreads();   // B tiles visible

        // ---- 2 k-steps x 4 tiles x 4 mfma ----
        #pragma unroll
        for (int tile = 0; tile < 4; ++tile) {
            const int bb = (tile*16 + lr)*PROW2 + g*8;
            bf16x8 bRH0 = *(const bf16x8*)&LB[grp][0][bb];
            bf16x8 bIH0 = *(const bf16x8*)&LB[grp][1][bb];
            bf16x8 bRH1 = *(const bf16x8*)&LB[grp][0][bb + 32];
            bf16x8 bIH1 = *(const bf16x8*)&LB[grp][1][bb + 32];
            accR[tile] = __builtin_amdgcn_mfma_f32_16x16x32_bf16(aRH0,  bRH0, accR[tile], 0,0,0);
            accR[tile] = __builtin_amdgcn_mfma_f32_16x16x32_bf16(aIHn0, bIH0, accR[tile], 0,0,0);
            accI[tile] = __builtin_amdgcn_mfma_f32_16x16x32_bf16(aRH0,  bIH0, accI[tile], 0,0,0);
            accI[tile] = __builtin_amdgcn_mfma_f32_16x16x32_bf16(aIH0,  bRH0, accI[tile], 0,0,0);
            accR[tile] = __builtin_amdgcn_mfma_f32_16x16x32_bf16(aRH1,  bRH1, accR[tile], 0,0,0);
            accR[tile] = __builtin_amdgcn_mfma_f32_16x16x32_bf16(aIHn1, bIH1, accR[tile], 0,0,0);
            accI[tile] = __builtin_amdgcn_mfma_f32_16x16x32_bf16(aRH1,  bIH1, accI[tile], 0,0,0);
            accI[tile] = __builtin_amdgcn_mfma_f32_16x16x32_bf16(aIH1,  bRH1, accI[tile], 0,0,0);
        }
    }

    // ---- split-K combine: group 0 deposits, group 1 adds + epilogue ----
    __syncthreads();
    float* cmb = (float*)&LB[0][0][0];   // 256*33*4 = 33,792B <= 36,864B
    if (grp == 0) {
        const int rbase = tg * 33;       // +1 pad -> conflict-free
        #pragma unroll
        for (int tile = 0; tile < 4; ++tile)
            #pragma unroll
            for (int r = 0; r < 4; ++r) {
                cmb[rbase + tile*8 + r]     = accR[tile][r];
                cmb[rbase + tile*8 + 4 + r] = accI[tile][r];
            }
    }
    __syncthreads();
    if (grp == 1) {
        const int rbase = tg * 33;
        #pragma unroll
        for (int tile = 0; tile < 4; ++tile)
            #pragma unroll
            for (int r = 0; r < 4; ++r) {
                accR[tile][r] += cmb[rbase + tile*8 + r];
                accI[tile][r] += cmb[rbase + tile*8 + 4 + r];
            }

        // ---- epilogue: D[o][s]; lane holds cols s=tile*16+lr, rows o=g*4+r
        const float2* b2 = (const float2*)b;
        const int obase = o0 + wave*16 + g*4;
        const int hh = obase >> 5, d0 = obase & 31;
        float bR[4], bI[4];
        #pragma unroll
        for (int r = 0; r < 4; ++r) { float2 bb = b2[obase + r]; bR[r] = bb.x; bI[r] = bb.y; }

        if (z == 0) {
            const float osc = 0.2550348677f;   // log2(e)/sqrt(32)
            unsigned short* pr = ws;
            unsigned short* pi = pr + PLANE_U;
            #pragma unroll
            for (int tile = 0; tile < 4; ++tile) {
                int s = s0 + tile*16 + lr;
                size_t idx = ((size_t)hh*S_LEN + s)*HD + d0;
                uint2 pkR, pkI;
                pkR.x = pk_bf16((accR[tile][0]+bR[0])*osc, (accR[tile][1]+bR[1])*osc);
                pkR.y = pk_bf16((accR[tile][2]+bR[2])*osc, (accR[tile][3]+bR[3])*osc);
                pkI.x = pk_bf16((accI[tile][0]+bI[0])*osc, (accI[tile][1]+bI[1])*osc);
                pkI.y = pk_bf16((accI[tile][2]+bI[2])*osc, (accI[tile][3]+bI[3])*osc);
                *(uint2*)&pr[idx] = pkR;
                *(uint2*)&pi[idx] = pkI;
            }
        } else if (z == 1) {
            unsigned short* kf = ws + 2*(size_t)PLANE_U;
            const int frag_re = (d0 >= 16) ? 1 : 0;
            const int bsel    = (d0 & 15) >> 3;
            const int e       = d0 & 7;
            #pragma unroll
            for (int tile = 0; tile < 4; ++tile) {
                int s = s0 + tile*16 + lr;              // key
                int c = s >> 5;
                int i = s & 31;
                int r = (i & ~12) | ((i & 4) << 1) | ((i & 8) >> 1);  // kappa
                int lane = bsel*32 + r;
                size_t base = ((size_t)(hh*64 + c)*4)*512 + lane*8 + e;
                uint2 pkR, pkI;
                pkR.x = pk_bf16(accR[tile][0]+bR[0], accR[tile][1]+bR[1]);
                pkR.y = pk_bf16(accR[tile][2]+bR[2], accR[tile][3]+bR[3]);
                pkI.x = pk_bf16(accI[tile][0]+bI[0], accI[tile][1]+bI[1]);
                pkI.y = pk_bf16(accI[tile][2]+bI[2], accI[tile][3]+bI[3]);
                *(uint2*)&kf[base + (size_t)frag_re*512]     = pkR;
                *(uint2*)&kf[base + (size_t)(2+frag_re)*512] = pkI;
            }
        } else {
            unsigned short* vf = ws + 4*(size_t)PLANE_U;
            const int bsel = lr >> 3;
            const int e    = lr & 7;
            #pragma unroll
            for (int tile = 0; tile < 4; ++tile) {
                int s = s0 + tile*16 + lr;              // key
                const int c       = s >> 5;
                const int frag_re = (s & 31) >= 16 ? 1 : 0;
                const size_t cb   = ((size_t)(hh*64 + c)*4)*512;
                #pragma unroll
                for (int r = 0; r < 4; ++r) {
                    int lane = bsel*32 + d0 + r;
                    size_t base = cb + (size_t)lane*8 + e;
                    vf[base + (size_t)frag_re*512]     =
                        (unsigned short)pk_bf16(accR[tile][r]+bR[r], 0.f);
                    vf[base + (size_t)(2+frag_re)*512] =
                        (unsigned short)pk_bf16(accI[tile][r]+bI[r], 0.f);
                }
            }
        }
    }
}

// ---------------- MFMA flash attention (unchanged — passing, <30us) ------
#define RROW 33

__global__ __launch_bounds__(256, 4)
void attn_mfma(const unsigned short* __restrict__ ws, float* __restrict__ out)
{
    const int bid   = blockIdx.x;       // 64 q-blocks x 16 heads
    const int h     = bid & (NH - 1);
    const int qblk  = bid >> 4;
    const int wave  = threadIdx.x >> 6;
    const int l     = threadIdx.x & 63;
    const int q     = l & 31;
    const int b     = l >> 5;

    const unsigned short* qr = ws + 0*(size_t)PLANE_U + (size_t)h*S_LEN*HD;
    const unsigned short* qi = ws + 1*(size_t)PLANE_U + (size_t)h*S_LEN*HD;
    const unsigned short* kf = ws + 2*(size_t)PLANE_U + ((size_t)h << 17);
    const unsigned short* vf = ws + 4*(size_t)PLANE_U + ((size_t)h << 17);

    const int q0 = qblk * 32;

    bf16x8 bQr_lo = *(const bf16x8*)&qr[(size_t)(q0 + q)*HD + b*8];
    bf16x8 bQr_hi = *(const bf16x8*)&qr[(size_t)(q0 + q)*HD + 16 + b*8];
    bf16x8 bQi_lo = *(const bf16x8*)&qi[(size_t)(q0 + q)*HD + b*8];
    bf16x8 bQi_hi = *(const bf16x8*)&qi[(size_t)(q0 + q)*HD + 16 + b*8];

    __shared__ __align__(16) float2 red[2*32*RROW];

    f32x16 accR, accI;
    #pragma unroll
    for (int r = 0; r < 16; ++r) { accR[r] = 0.f; accI[r] = 0.f; }
    float lsum = 0.f;

    const f32x16 z16 = {0,0,0,0,0,0,0,0,0,0,0,0,0,0,0,0};
    const int kbeg = wave * 512;
    for (int k0 = kbeg; k0 < kbeg + 512; k0 += 32) {
        const size_t fb = (size_t)(k0 >> 5) * 2048 + l*8;

        bf16x8 aVr_lo = *(const bf16x8*)&vf[fb];
        bf16x8 aVr_hi = *(const bf16x8*)&vf[fb + 512];
        bf16x8 aVi_lo = *(const bf16x8*)&vf[fb + 1024];
        bf16x8 aVi_hi = *(const bf16x8*)&vf[fb + 1536];

        bf16x8 aKr_lo = *(const bf16x8*)&kf[fb];
        bf16x8 aKr_hi = *(const bf16x8*)&kf[fb + 512];
        bf16x8 aKi_lo = *(const bf16x8*)&kf[fb + 1024];
        bf16x8 aKi_hi = *(const bf16x8*)&kf[fb + 1536];
        bf16x8 aKin_lo, aKin_hi;
        #pragma unroll
        for (int j = 0; j < 4; ++j) {
            ((unsigned int*)&aKin_lo)[j] = ((const unsigned int*)&aKi_lo)[j] ^ 0x80008000u;
            ((unsigned int*)&aKin_hi)[j] = ((const unsigned int*)&aKi_hi)[j] ^ 0x80008000u;
        }
        f32x16 sR = __builtin_amdgcn_mfma_f32_32x32x16_bf16(aKr_lo,  bQr_lo, z16, 0, 0, 0);
        f32x16 sI = __builtin_amdgcn_mfma_f32_32x32x16_bf16(aKin_lo, bQr_lo, z16, 0, 0, 0);
        sR = __builtin_amdgcn_mfma_f32_32x32x16_bf16(aKr_hi,  bQr_hi, sR, 0, 0, 0);
        sI = __builtin_amdgcn_mfma_f32_32x32x16_bf16(aKin_hi, bQr_hi, sI, 0, 0, 0);
        sR = __builtin_amdgcn_mfma_f32_32x32x16_bf16(aKi_lo,  bQi_lo, sR, 0, 0, 0);
        sI = __builtin_amdgcn_mfma_f32_32x32x16_bf16(aKr_lo,  bQi_lo, sI, 0, 0, 0);
        sR = __builtin_amdgcn_mfma_f32_32x32x16_bf16(aKi_hi,  bQi_hi, sR, 0, 0, 0);
        sI = __builtin_amdgcn_mfma_f32_32x32x16_bf16(aKr_hi,  bQi_hi, sI, 0, 0, 0);

        bf16x8 bP1, bP2;
        unsigned int* p1 = (unsigned int*)&bP1;
        unsigned int* p2 = (unsigned int*)&bP2;
        #pragma unroll
        for (int r2 = 0; r2 < 8; ++r2) {
            int r = 2*r2;
            float v0 = EXP2(__builtin_amdgcn_sqrtf(fmaf(sR[r],   sR[r],   sI[r]*sI[r])));
            float v1 = EXP2(__builtin_amdgcn_sqrtf(fmaf(sR[r+1], sR[r+1], sI[r+1]*sI[r+1])));
            lsum += v0 + v1;
            if (r2 < 4) p1[r2]     = pk_bf16(v0, v1);
            else        p2[r2 - 4] = pk_bf16(v0, v1);
        }
        accR = __builtin_amdgcn_mfma_f32_32x32x16_bf16(aVr_lo, bP1, accR, 0, 0, 0);
        accI = __builtin_amdgcn_mfma_f32_32x32x16_bf16(aVi_lo, bP1, accI, 0, 0, 0);
        accR = __builtin_amdgcn_mfma_f32_32x32x16_bf16(aVr_hi, bP2, accR, 0, 0, 0);
        accI = __builtin_amdgcn_mfma_f32_32x32x16_bf16(aVi_hi, bP2, accI, 0, 0, 0);
    }

    lsum += __shfl_xor(lsum, 32);

    const int rrow = ((wave & 1) * 32 + q) * RROW;
    __syncthreads();
    if (wave < 2) {
        #pragma unroll
        for (int r = 0; r < 16; ++r) {
            int d = (r & 3) + 8*(r >> 2) + 4*b;
            red[rrow + d] = make_float2(accR[r], accI[r]);
        }
        if (b == 0) red[rrow + 32].x = lsum;
    }
    __syncthreads();
    if (wave >= 2) {
        #pragma unroll
        for (int r = 0; r < 16; ++r) {
            int d = (r & 3) + 8*(r >> 2) + 4*b;
            float2 v = red[rrow + d];
            v.x += accR[r]; v.y += accI[r];
            red[rrow + d] = v;
        }
        if (b == 0) red[rrow + 32].x += lsum;
    }
    __syncthreads();

    {
        const int i  = threadIdx.x;
        const int oq = i >> 3;
        const int d0 = (i & 7) * 4;
        float sl = red[oq*RROW + 32].x + red[(32 + oq)*RROW + 32].x;
        float inv = 1.0f / sl;
        float2* o2 = (float2*)out;
        #pragma unroll
        for (int dd = 0; dd < 4; ++dd) {
            int d = d0 + dd;
            float2 v0 = red[oq*RROW + d];
            float2 v1 = red[(32 + oq)*RROW + d];
            o2[(size_t)(q0 + oq)*C_DIM + h*HD + d] =
                make_float2((v0.x + v1.x)*inv, (v0.y + v1.y)*inv);
        }
    }
}

extern "C" void kernel_launch(void* const* d_in, const int* in_sizes, int n_in,
                              void* d_out, int out_size, void* d_ws, size_t ws_size,
                              hipStream_t stream)
{
    const float* Q  = (const float*)d_in[0];
    const float* V  = (const float*)d_in[1];
    const float* K  = (const float*)d_in[2];
    const float* Wq = (const float*)d_in[3];
    const float* bq = (const float*)d_in[4];
    const float* Wk = (const float*)d_in[5];
    const float* bk = (const float*)d_in[6];
    const float* Wv = (const float*)d_in[7];
    const float* bv = (const float*)d_in[8];
    unsigned short* ws = (unsigned short*)d_ws;   // 12MB planes + 3MB WF
    float* out = (float*)d_out;

    wcvt<<<384, 256, 0, stream>>>(Wq, Wk, Wv, ws);
    proj_mfma<<<dim3(S_LEN/64, C_DIM/64, 3), 512, 0, stream>>>(Q, V, K, bq, bk, bv, ws);
    attn_mfma<<<dim3(64*NH), 256, 0, stream>>>(ws, out);
}

// Round 20
// 85.929 us; speedup vs baseline: 1.1433x; 1.1433x over previous
//
#include <hip/hip_runtime.h>
#include <hip/hip_bf16.h>
#include <math.h>

#define S_LEN 2048
#define C_DIM 512
#define NH 16
#define HD 32
#define PLANE_U (NH * S_LEN * HD)   // 1,048,576 ushorts = 2MB per plane
#define WPL 262144                  // 512*512 ushorts per W plane

typedef __attribute__((ext_vector_type(8)))  short bf16x8;
typedef __attribute__((ext_vector_type(4)))  float f32x4;
typedef __attribute__((ext_vector_type(16))) float f32x16;
typedef __attribute__((ext_vector_type(4)))  unsigned int u32x4;

#if __has_builtin(__builtin_amdgcn_exp2f)
#define EXP2(x) __builtin_amdgcn_exp2f(x)
#else
#define EXP2(x) exp2f(x)
#endif

// pack 2 floats -> 2 bf16 in one dword via v_cvt_pk_bf16_f32 (RNE); a = low
__device__ __forceinline__ unsigned int pk_bf16(float a, float b) {
    float2 f; f.x = a; f.y = b;
    __hip_bfloat162 t = __float22bfloat162_rn(f);
    return *reinterpret_cast<unsigned int*>(&t);
}

// ---------------- W pre-conversion: fp32 -> bf16 RNE planes ---------------
// WF (at ws + 6*PLANE_U): plane z*2+{0:re,1:im}, each [o:512][k:512] ushort.
__global__ __launch_bounds__(256)
void wcvt(const float* __restrict__ Wq, const float* __restrict__ Wk,
          const float* __restrict__ Wv, unsigned short* __restrict__ ws)
{
    const int tid = blockIdx.x*256 + threadIdx.x;   // 98304 total
    const int z   = tid >> 15;
    const int rem = tid & 32767;
    const int row = rem >> 6;
    const int kc  = (rem & 63) * 8;                 // 8 complex
    const float2* w2 = (const float2*)(z == 0 ? Wq : (z == 1 ? Wk : Wv));
    const float4* s4 = (const float4*)(w2 + (size_t)row*C_DIM + kc);
    float4 f0 = s4[0], f1 = s4[1], f2v = s4[2], f3 = s4[3];
    float re[8] = {f0.x,f0.z,f1.x,f1.z,f2v.x,f2v.z,f3.x,f3.z};
    float im[8] = {f0.y,f0.w,f1.y,f1.w,f2v.y,f2v.w,f3.y,f3.w};
    u32x4 rh, ih;
    #pragma unroll
    for (int p2 = 0; p2 < 4; ++p2) {
        rh[p2] = pk_bf16(re[2*p2], re[2*p2+1]);
        ih[p2] = pk_bf16(im[2*p2], im[2*p2+1]);
    }
    unsigned short* wf = ws + 6*(size_t)PLANE_U;
    const size_t off = (size_t)row*C_DIM + kc;
    *(u32x4*)&wf[(size_t)(z*2+0)*WPL + off] = rh;
    *(u32x4*)&wf[(size_t)(z*2+1)*WPL + off] = ih;
}

// ---------------- projection: complex GEMM, register-prefetch pipeline ----
// D = W·X^T, hi-only RNE (4 mfma/tile/k-step), 64x64 tile, BK=64, 256 thr.
// Software pipeline: hold the CURRENT B tile (cvt'd) + A fragments in regs;
// per iteration {barrier, store B->LDS, barrier, PREFETCH next B+A, 32 mfma}
// so the ~500cy global-load latency hides under the MFMA block instead of
// sitting on the critical path (round-18 exposed it every iteration).
// z==0 (q): -> natural [h][s][d], PRE-SCALED by log2(e)/sqrt(32)
// z==1 (k): -> fragment-order KF[h][c][frag][lane][8], kappa pre-folded
// z==2 (v): -> fragment-order VF[h][c][frag][lane][8] (from D[o][s])
#define PROW2 72   // padded LDS row stride in ushorts (144B)

__global__ __launch_bounds__(256)
void proj_mfma(const float* __restrict__ Q, const float* __restrict__ V,
               const float* __restrict__ K,
               const float* __restrict__ bq, const float* __restrict__ bk,
               const float* __restrict__ bv,
               unsigned short* __restrict__ ws)
{
    const int z = blockIdx.z;
    const float *X, *b;
    if (z == 0)      { X = Q; b = bq; }
    else if (z == 1) { X = K; b = bk; }
    else             { X = V; b = bv; }

    const int s0 = blockIdx.x * 64;
    const int o0 = blockIdx.y * 64;

    const float2* Bsrc = (const float2*)X;
    const unsigned short* wf = ws + 6*(size_t)PLANE_U;
    const size_t pb = (size_t)z*2*WPL;

    __shared__ __align__(16) unsigned short LBrh[64*PROW2], LBih[64*PROW2];

    const int t    = threadIdx.x;
    const int wave = t >> 6;
    const int lr   = t & 15;
    const int g    = (t & 63) >> 4;
    const int srow = t >> 2;        // B staging row 0..63
    const int skc  = (t & 3) * 16;  // B staging k chunk (16 complex)

    const f32x4 zf = {0.f,0.f,0.f,0.f};
    f32x4 accR[4], accI[4];
    #pragma unroll
    for (int i = 0; i < 4; ++i) { accR[i] = zf; accI[i] = zf; }

    const size_t arow = (size_t)(o0 + wave*16 + lr) * C_DIM;

    struct Bregs { u32x4 rhA, rhB, ihA, ihB; };
    struct Aregs { bf16x8 rh0, rh1, ih0, ih1; };

    auto loadB = [&](int k0) {
        Bregs r;
        const float4* s4 = (const float4*)(Bsrc + (size_t)(s0 + srow)*C_DIM + k0 + skc);
        #pragma unroll
        for (int p2 = 0; p2 < 4; ++p2) {
            float4 fa = s4[2*p2], fb = s4[2*p2+1];
            unsigned int rw = pk_bf16(fa.x, fa.z);
            unsigned int r2 = pk_bf16(fb.x, fb.z);
            unsigned int iw = pk_bf16(fa.y, fa.w);
            unsigned int i2 = pk_bf16(fb.y, fb.w);
            if (p2 < 2) { r.rhA[2*p2] = rw; r.rhA[2*p2+1] = r2; r.ihA[2*p2] = iw; r.ihA[2*p2+1] = i2; }
            else        { r.rhB[2*(p2-2)] = rw; r.rhB[2*(p2-2)+1] = r2; r.ihB[2*(p2-2)] = iw; r.ihB[2*(p2-2)+1] = i2; }
        }
        return r;
    };
    auto loadA = [&](int k0) {
        Aregs a;
        const size_t ak = arow + k0 + g*8;
        a.rh0 = *(const bf16x8*)&wf[pb + ak];
        a.rh1 = *(const bf16x8*)&wf[pb + ak + 32];
        a.ih0 = *(const bf16x8*)&wf[pb + WPL + ak];
        a.ih1 = *(const bf16x8*)&wf[pb + WPL + ak + 32];
        return a;
    };

    Bregs bcur = loadB(0);
    Aregs acur = loadA(0);

    #pragma unroll
    for (int it = 0; it < 8; ++it) {
        __syncthreads();   // previous B tile fully consumed
        {
            int wb = srow*PROW2 + skc;
            *(u32x4*)&LBrh[wb]     = bcur.rhA;
            *(u32x4*)&LBrh[wb + 8] = bcur.rhB;
            *(u32x4*)&LBih[wb]     = bcur.ihA;
            *(u32x4*)&LBih[wb + 8] = bcur.ihB;
        }
        __syncthreads();   // B tile visible

        // ---- PREFETCH next iteration's B + A (hides under the MFMAs) ----
        Bregs bnext; Aregs anext;
        if (it < 7) {
            bnext = loadB((it+1)*64);
            anext = loadA((it+1)*64);
        }

        // ---- negated imag A for this iteration ----
        bf16x8 aIHn0, aIHn1;
        #pragma unroll
        for (int j = 0; j < 4; ++j) {
            ((unsigned int*)&aIHn0)[j] = ((const unsigned int*)&acur.ih0)[j] ^ 0x80008000u;
            ((unsigned int*)&aIHn1)[j] = ((const unsigned int*)&acur.ih1)[j] ^ 0x80008000u;
        }

        // ---- 2 k-steps x 4 tiles x 4 mfma ----
        #pragma unroll
        for (int tile = 0; tile < 4; ++tile) {
            const int bb = (tile*16 + lr)*PROW2 + g*8;
            bf16x8 bRH0 = *(const bf16x8*)&LBrh[bb];
            bf16x8 bIH0 = *(const bf16x8*)&LBih[bb];
            bf16x8 bRH1 = *(const bf16x8*)&LBrh[bb + 32];
            bf16x8 bIH1 = *(const bf16x8*)&LBih[bb + 32];
            accR[tile] = __builtin_amdgcn_mfma_f32_16x16x32_bf16(acur.rh0, bRH0, accR[tile], 0,0,0);
            accR[tile] = __builtin_amdgcn_mfma_f32_16x16x32_bf16(aIHn0,    bIH0, accR[tile], 0,0,0);
            accI[tile] = __builtin_amdgcn_mfma_f32_16x16x32_bf16(acur.rh0, bIH0, accI[tile], 0,0,0);
            accI[tile] = __builtin_amdgcn_mfma_f32_16x16x32_bf16(acur.ih0, bRH0, accI[tile], 0,0,0);
            accR[tile] = __builtin_amdgcn_mfma_f32_16x16x32_bf16(acur.rh1, bRH1, accR[tile], 0,0,0);
            accR[tile] = __builtin_amdgcn_mfma_f32_16x16x32_bf16(aIHn1,    bIH1, accR[tile], 0,0,0);
            accI[tile] = __builtin_amdgcn_mfma_f32_16x16x32_bf16(acur.rh1, bIH1, accI[tile], 0,0,0);
            accI[tile] = __builtin_amdgcn_mfma_f32_16x16x32_bf16(acur.ih1, bRH1, accI[tile], 0,0,0);
        }
        if (it < 7) { bcur = bnext; acur = anext; }
    }

    // ---- epilogue: D[o][s]; lane holds cols s = tile*16+lr, rows o = g*4+r
    const float2* b2 = (const float2*)b;
    const int obase = o0 + wave*16 + g*4;
    const int hh = obase >> 5, d0 = obase & 31;
    float bR[4], bI[4];
    #pragma unroll
    for (int r = 0; r < 4; ++r) { float2 bb = b2[obase + r]; bR[r] = bb.x; bI[r] = bb.y; }

    if (z == 0) {
        const float osc = 0.2550348677f;   // log2(e)/sqrt(32)
        unsigned short* pr = ws;
        unsigned short* pi = pr + PLANE_U;
        #pragma unroll
        for (int tile = 0; tile < 4; ++tile) {
            int s = s0 + tile*16 + lr;
            size_t idx = ((size_t)hh*S_LEN + s)*HD + d0;
            uint2 pkR, pkI;
            pkR.x = pk_bf16((accR[tile][0]+bR[0])*osc, (accR[tile][1]+bR[1])*osc);
            pkR.y = pk_bf16((accR[tile][2]+bR[2])*osc, (accR[tile][3]+bR[3])*osc);
            pkI.x = pk_bf16((accI[tile][0]+bI[0])*osc, (accI[tile][1]+bI[1])*osc);
            pkI.y = pk_bf16((accI[tile][2]+bI[2])*osc, (accI[tile][3]+bI[3])*osc);
            *(uint2*)&pr[idx] = pkR;
            *(uint2*)&pi[idx] = pkI;
        }
    } else if (z == 1) {
        // KF[h][c][frag][lane][8]: frag by d half; lane = bsel*32 + kappa(key)
        unsigned short* kf = ws + 2*(size_t)PLANE_U;
        const int frag_re = (d0 >= 16) ? 1 : 0;
        const int bsel    = (d0 & 15) >> 3;
        const int e       = d0 & 7;                 // 0 or 4
        #pragma unroll
        for (int tile = 0; tile < 4; ++tile) {
            int s = s0 + tile*16 + lr;              // key
            int c = s >> 5;
            int i = s & 31;
            int r = (i & ~12) | ((i & 4) << 1) | ((i & 8) >> 1);  // kappa
            int lane = bsel*32 + r;
            size_t base = ((size_t)(hh*64 + c)*4)*512 + lane*8 + e;
            uint2 pkR, pkI;
            pkR.x = pk_bf16(accR[tile][0]+bR[0], accR[tile][1]+bR[1]);
            pkR.y = pk_bf16(accR[tile][2]+bR[2], accR[tile][3]+bR[3]);
            pkI.x = pk_bf16(accI[tile][0]+bI[0], accI[tile][1]+bI[1]);
            pkI.y = pk_bf16(accI[tile][2]+bI[2], accI[tile][3]+bI[3]);
            *(uint2*)&kf[base + (size_t)frag_re*512]     = pkR;
            *(uint2*)&kf[base + (size_t)(2+frag_re)*512] = pkI;
        }
    } else {
        // VF[h][c][frag][lane][8]: frag by key half; lane = (lr>>3)*32 + d
        unsigned short* vf = ws + 4*(size_t)PLANE_U;
        const int bsel = lr >> 3;
        const int e    = lr & 7;
        #pragma unroll
        for (int tile = 0; tile < 4; ++tile) {
            int s = s0 + tile*16 + lr;              // key
            const int c       = s >> 5;
            const int frag_re = (s & 31) >= 16 ? 1 : 0;
            const size_t cb   = ((size_t)(hh*64 + c)*4)*512;
            #pragma unroll
            for (int r = 0; r < 4; ++r) {
                int lane = bsel*32 + d0 + r;
                size_t base = cb + (size_t)lane*8 + e;
                vf[base + (size_t)frag_re*512]     =
                    (unsigned short)pk_bf16(accR[tile][r]+bR[r], 0.f);
                vf[base + (size_t)(2+frag_re)*512] =
                    (unsigned short)pk_bf16(accI[tile][r]+bI[r], 0.f);
            }
        }
    }
}

// ---------------- MFMA flash attention (unchanged — passing, <30us) ------
#define RROW 33

__global__ __launch_bounds__(256, 4)
void attn_mfma(const unsigned short* __restrict__ ws, float* __restrict__ out)
{
    const int bid   = blockIdx.x;       // 64 q-blocks x 16 heads
    const int h     = bid & (NH - 1);
    const int qblk  = bid >> 4;
    const int wave  = threadIdx.x >> 6;
    const int l     = threadIdx.x & 63;
    const int q     = l & 31;
    const int b     = l >> 5;

    const unsigned short* qr = ws + 0*(size_t)PLANE_U + (size_t)h*S_LEN*HD;
    const unsigned short* qi = ws + 1*(size_t)PLANE_U + (size_t)h*S_LEN*HD;
    const unsigned short* kf = ws + 2*(size_t)PLANE_U + ((size_t)h << 17);
    const unsigned short* vf = ws + 4*(size_t)PLANE_U + ((size_t)h << 17);

    const int q0 = qblk * 32;

    bf16x8 bQr_lo = *(const bf16x8*)&qr[(size_t)(q0 + q)*HD + b*8];
    bf16x8 bQr_hi = *(const bf16x8*)&qr[(size_t)(q0 + q)*HD + 16 + b*8];
    bf16x8 bQi_lo = *(const bf16x8*)&qi[(size_t)(q0 + q)*HD + b*8];
    bf16x8 bQi_hi = *(const bf16x8*)&qi[(size_t)(q0 + q)*HD + 16 + b*8];

    __shared__ __align__(16) float2 red[2*32*RROW];

    f32x16 accR, accI;
    #pragma unroll
    for (int r = 0; r < 16; ++r) { accR[r] = 0.f; accI[r] = 0.f; }
    float lsum = 0.f;

    const f32x16 z16 = {0,0,0,0,0,0,0,0,0,0,0,0,0,0,0,0};
    const int kbeg = wave * 512;
    for (int k0 = kbeg; k0 < kbeg + 512; k0 += 32) {
        const size_t fb = (size_t)(k0 >> 5) * 2048 + l*8;

        bf16x8 aVr_lo = *(const bf16x8*)&vf[fb];
        bf16x8 aVr_hi = *(const bf16x8*)&vf[fb + 512];
        bf16x8 aVi_lo = *(const bf16x8*)&vf[fb + 1024];
        bf16x8 aVi_hi = *(const bf16x8*)&vf[fb + 1536];

        bf16x8 aKr_lo = *(const bf16x8*)&kf[fb];
        bf16x8 aKr_hi = *(const bf16x8*)&kf[fb + 512];
        bf16x8 aKi_lo = *(const bf16x8*)&kf[fb + 1024];
        bf16x8 aKi_hi = *(const bf16x8*)&kf[fb + 1536];
        bf16x8 aKin_lo, aKin_hi;
        #pragma unroll
        for (int j = 0; j < 4; ++j) {
            ((unsigned int*)&aKin_lo)[j] = ((const unsigned int*)&aKi_lo)[j] ^ 0x80008000u;
            ((unsigned int*)&aKin_hi)[j] = ((const unsigned int*)&aKi_hi)[j] ^ 0x80008000u;
        }
        f32x16 sR = __builtin_amdgcn_mfma_f32_32x32x16_bf16(aKr_lo,  bQr_lo, z16, 0, 0, 0);
        f32x16 sI = __builtin_amdgcn_mfma_f32_32x32x16_bf16(aKin_lo, bQr_lo, z16, 0, 0, 0);
        sR = __builtin_amdgcn_mfma_f32_32x32x16_bf16(aKr_hi,  bQr_hi, sR, 0, 0, 0);
        sI = __builtin_amdgcn_mfma_f32_32x32x16_bf16(aKin_hi, bQr_hi, sI, 0, 0, 0);
        sR = __builtin_amdgcn_mfma_f32_32x32x16_bf16(aKi_lo,  bQi_lo, sR, 0, 0, 0);
        sI = __builtin_amdgcn_mfma_f32_32x32x16_bf16(aKr_lo,  bQi_lo, sI, 0, 0, 0);
        sR = __builtin_amdgcn_mfma_f32_32x32x16_bf16(aKi_hi,  bQi_hi, sR, 0, 0, 0);
        sI = __builtin_amdgcn_mfma_f32_32x32x16_bf16(aKr_hi,  bQi_hi, sI, 0, 0, 0);

        bf16x8 bP1, bP2;
        unsigned int* p1 = (unsigned int*)&bP1;
        unsigned int* p2 = (unsigned int*)&bP2;
        #pragma unroll
        for (int r2 = 0; r2 < 8; ++r2) {
            int r = 2*r2;
            float v0 = EXP2(__builtin_amdgcn_sqrtf(fmaf(sR[r],   sR[r],   sI[r]*sI[r])));
            float v1 = EXP2(__builtin_amdgcn_sqrtf(fmaf(sR[r+1], sR[r+1], sI[r+1]*sI[r+1])));
            lsum += v0 + v1;
            if (r2 < 4) p1[r2]     = pk_bf16(v0, v1);
            else        p2[r2 - 4] = pk_bf16(v0, v1);
        }
        accR = __builtin_amdgcn_mfma_f32_32x32x16_bf16(aVr_lo, bP1, accR, 0, 0, 0);
        accI = __builtin_amdgcn_mfma_f32_32x32x16_bf16(aVi_lo, bP1, accI, 0, 0, 0);
        accR = __builtin_amdgcn_mfma_f32_32x32x16_bf16(aVr_hi, bP2, accR, 0, 0, 0);
        accI = __builtin_amdgcn_mfma_f32_32x32x16_bf16(aVi_hi, bP2, accI, 0, 0, 0);
    }

    lsum += __shfl_xor(lsum, 32);

    const int rrow = ((wave & 1) * 32 + q) * RROW;
    __syncthreads();
    if (wave < 2) {
        #pragma unroll
        for (int r = 0; r < 16; ++r) {
            int d = (r & 3) + 8*(r >> 2) + 4*b;
            red[rrow + d] = make_float2(accR[r], accI[r]);
        }
        if (b == 0) red[rrow + 32].x = lsum;
    }
    __syncthreads();
    if (wave >= 2) {
        #pragma unroll
        for (int r = 0; r < 16; ++r) {
            int d = (r & 3) + 8*(r >> 2) + 4*b;
            float2 v = red[rrow + d];
            v.x += accR[r]; v.y += accI[r];
            red[rrow + d] = v;
        }
        if (b == 0) red[rrow + 32].x += lsum;
    }
    __syncthreads();

    {
        const int i  = threadIdx.x;
        const int oq = i >> 3;
        const int d0 = (i & 7) * 4;
        float sl = red[oq*RROW + 32].x + red[(32 + oq)*RROW + 32].x;
        float inv = 1.0f / sl;
        float2* o2 = (float2*)out;
        #pragma unroll
        for (int dd = 0; dd < 4; ++dd) {
            int d = d0 + dd;
            float2 v0 = red[oq*RROW + d];
            float2 v1 = red[(32 + oq)*RROW + d];
            o2[(size_t)(q0 + oq)*C_DIM + h*HD + d] =
                make_float2((v0.x + v1.x)*inv, (v0.y + v1.y)*inv);
        }
    }
}

extern "C" void kernel_launch(void* const* d_in, const int* in_sizes, int n_in,
                              void* d_out, int out_size, void* d_ws, size_t ws_size,
                              hipStream_t stream)
{
    const float* Q  = (const float*)d_in[0];
    const float* V  = (const float*)d_in[1];
    const float* K  = (const float*)d_in[2];
    const float* Wq = (const float*)d_in[3];
    const float* bq = (const float*)d_in[4];
    const float* Wk = (const float*)d_in[5];
    const float* bk = (const float*)d_in[6];
    const float* Wv = (const float*)d_in[7];
    const float* bv = (const float*)d_in[8];
    unsigned short* ws = (unsigned short*)d_ws;   // 12MB planes + 3MB WF
    float* out = (float*)d_out;

    wcvt<<<384, 256, 0, stream>>>(Wq, Wk, Wv, ws);
    proj_mfma<<<dim3(S_LEN/64, C_DIM/64, 3), 256, 0, stream>>>(Q, V, K, bq, bk, bv, ws);
    attn_mfma<<<dim3(64*NH), 256, 0, stream>>>(ws, out);
}

// Round 21
// 78.207 us; speedup vs baseline: 1.2562x; 1.0987x over previous
//
#include <hip/hip_runtime.h>
#include <hip/hip_bf16.h>
#include <math.h>

#define S_LEN 2048
#define C_DIM 512
#define NH 16
#define HD 32
#define PLANE_U (NH * S_LEN * HD)   // 1,048,576 ushorts = 2MB per plane
#define XF_OFF  (6*(size_t)PLANE_U)   // X fragment planes: 3z x {re,im} x 2MB
#define WF_OFF  (12*(size_t)PLANE_U)  // W fragment planes: 3z x {re,im} x 512KB
#define WPLF 262144                   // 512*512 ushorts per W plane

typedef __attribute__((ext_vector_type(8)))  short bf16x8;
typedef __attribute__((ext_vector_type(4)))  float f32x4;
typedef __attribute__((ext_vector_type(16))) float f32x16;
typedef __attribute__((ext_vector_type(4)))  unsigned int u32x4;

#if __has_builtin(__builtin_amdgcn_exp2f)
#define EXP2(x) __builtin_amdgcn_exp2f(x)
#else
#define EXP2(x) exp2f(x)
#endif

// pack 2 floats -> 2 bf16 in one dword via v_cvt_pk_bf16_f32 (RNE); a = low
__device__ __forceinline__ unsigned int pk_bf16(float a, float b) {
    float2 f; f.x = a; f.y = b;
    __hip_bfloat162 t = __float22bfloat162_rn(f);
    return *reinterpret_cast<unsigned int*>(&t);
}

// ---------------- X pre-conversion: fp32 -> bf16 B-FRAGMENT-ORDER planes --
// XF[z][{re,im}][sb:128][kc:16][lane:64][e:8]; lane = g*16+lr holds
// X[s = sb*16+lr][k = kc*32+g*8+e]. proj's B loads = contiguous 1KB/wave.
__global__ __launch_bounds__(256)
void xcvt(const float* __restrict__ Q, const float* __restrict__ K,
          const float* __restrict__ V, unsigned short* __restrict__ ws)
{
    const int tid  = blockIdx.x*256 + threadIdx.x;   // 393,216 total
    const int z    = tid >> 17;
    const int rem  = tid & 131071;
    const int kidx = rem >> 11;          // 0..63 (k-chunk of 8)
    const int s    = rem & 2047;
    const int k    = kidx * 8;
    const float2* x2 = (const float2*)(z == 0 ? Q : (z == 1 ? K : V));
    const float4* s4 = (const float4*)(x2 + (size_t)s*C_DIM + k);
    float4 f0 = s4[0], f1 = s4[1], f2v = s4[2], f3 = s4[3];
    u32x4 rh, ih;
    rh[0] = pk_bf16(f0.x, f0.z); rh[1] = pk_bf16(f1.x, f1.z);
    rh[2] = pk_bf16(f2v.x, f2v.z); rh[3] = pk_bf16(f3.x, f3.z);
    ih[0] = pk_bf16(f0.y, f0.w); ih[1] = pk_bf16(f1.y, f1.w);
    ih[2] = pk_bf16(f2v.y, f2v.w); ih[3] = pk_bf16(f3.y, f3.w);
    const int sb = s >> 4, lr = s & 15, g = kidx & 3, kc = kidx >> 2;
    const size_t off = ((size_t)(sb*16 + kc)*64 + g*16 + lr)*8;
    unsigned short* base = ws + XF_OFF + (size_t)z*2*PLANE_U;
    *(u32x4*)&base[off]           = rh;
    *(u32x4*)&base[PLANE_U + off] = ih;
}

// ---------------- W pre-conversion: fp32 -> bf16 A-FRAGMENT-ORDER planes --
// WFB[z][{re,im}][ob:32][kc:16][lane:64][e:8]; lane = g*16+lr holds
// W[o = ob*16+lr][k = kc*32+g*8+e].
__global__ __launch_bounds__(256)
void wcvt(const float* __restrict__ Wq, const float* __restrict__ Wk,
          const float* __restrict__ Wv, unsigned short* __restrict__ ws)
{
    const int tid  = blockIdx.x*256 + threadIdx.x;   // 98,304 total
    const int z    = tid >> 15;
    const int rem  = tid & 32767;
    const int kidx = rem >> 9;           // 0..63
    const int o    = rem & 511;
    const int k    = kidx * 8;
    const float2* w2 = (const float2*)(z == 0 ? Wq : (z == 1 ? Wk : Wv));
    const float4* s4 = (const float4*)(w2 + (size_t)o*C_DIM + k);
    float4 f0 = s4[0], f1 = s4[1], f2v = s4[2], f3 = s4[3];
    u32x4 rh, ih;
    rh[0] = pk_bf16(f0.x, f0.z); rh[1] = pk_bf16(f1.x, f1.z);
    rh[2] = pk_bf16(f2v.x, f2v.z); rh[3] = pk_bf16(f3.x, f3.z);
    ih[0] = pk_bf16(f0.y, f0.w); ih[1] = pk_bf16(f1.y, f1.w);
    ih[2] = pk_bf16(f2v.y, f2v.w); ih[3] = pk_bf16(f3.y, f3.w);
    const int ob = o >> 4, lr = o & 15, g = kidx & 3, kc = kidx >> 2;
    const size_t off = ((size_t)(ob*16 + kc)*64 + g*16 + lr)*8;
    unsigned short* base = ws + WF_OFF + (size_t)z*2*WPLF;
    *(u32x4*)&base[off]       = rh;
    *(u32x4*)&base[WPLF + off] = ih;
}

// ---------------- projection: barrier-free complex GEMM ------------------
// D = W·X^T, hi-only RNE. NO LDS, NO __syncthreads: both operands load as
// contiguous 1KB wave-fragments from the pre-converted XF/WFB planes (same
// structure as attn's main loop). Wave = 16 o-rows x 32 s-cols; grid
// 64(s) x 8(o) x 3(z) = 1536 blocks -> 24 free-running waves/CU.
// z==0 (q): -> natural [h][s][d], PRE-SCALED by log2(e)/sqrt(32)
// z==1 (k): -> fragment-order KF[h][c][frag][lane][8], kappa pre-folded
// z==2 (v): -> fragment-order VF[h][c][frag][lane][8] (from D[o][s])
__global__ __launch_bounds__(256)
void proj_mfma(const float* __restrict__ bq, const float* __restrict__ bk,
               const float* __restrict__ bv,
               unsigned short* __restrict__ ws)
{
    const int z = blockIdx.z;
    const float* b = (z == 0) ? bq : (z == 1 ? bk : bv);

    const int s0 = blockIdx.x * 32;
    const int o0 = blockIdx.y * 64;

    const unsigned short* xfR = ws + XF_OFF + (size_t)z*2*PLANE_U;
    const unsigned short* xfI = xfR + PLANE_U;
    const unsigned short* wfR = ws + WF_OFF + (size_t)z*2*WPLF;
    const unsigned short* wfI = wfR + WPLF;

    const int t    = threadIdx.x;
    const int wave = t >> 6;
    const int lane = t & 63;
    const int lr   = t & 15;
    const int g    = (t & 63) >> 4;

    const int ob = (o0 >> 4) + wave;    // W row-block
    const int sb = s0 >> 4;             // X row-blocks sb, sb+1

    const f32x4 zf = {0.f,0.f,0.f,0.f};
    f32x4 accR[2], accI[2];
    #pragma unroll
    for (int i = 0; i < 2; ++i) { accR[i] = zf; accI[i] = zf; }

    for (int kc = 0; kc < 16; ++kc) {
        const size_t aoff = ((size_t)(ob*16 + kc)*64 + lane)*8;
        bf16x8 aRH = *(const bf16x8*)&wfR[aoff];
        bf16x8 aIH = *(const bf16x8*)&wfI[aoff];
        bf16x8 aIHn;
        #pragma unroll
        for (int j = 0; j < 4; ++j)
            ((unsigned int*)&aIHn)[j] = ((const unsigned int*)&aIH)[j] ^ 0x80008000u;

        const size_t b0 = ((size_t)(sb*16 + kc)*64 + lane)*8;
        const size_t b1 = ((size_t)((sb+1)*16 + kc)*64 + lane)*8;
        bf16x8 bRH0 = *(const bf16x8*)&xfR[b0];
        bf16x8 bIH0 = *(const bf16x8*)&xfI[b0];
        bf16x8 bRH1 = *(const bf16x8*)&xfR[b1];
        bf16x8 bIH1 = *(const bf16x8*)&xfI[b1];

        accR[0] = __builtin_amdgcn_mfma_f32_16x16x32_bf16(aRH,  bRH0, accR[0], 0,0,0);
        accR[0] = __builtin_amdgcn_mfma_f32_16x16x32_bf16(aIHn, bIH0, accR[0], 0,0,0);
        accI[0] = __builtin_amdgcn_mfma_f32_16x16x32_bf16(aRH,  bIH0, accI[0], 0,0,0);
        accI[0] = __builtin_amdgcn_mfma_f32_16x16x32_bf16(aIH,  bRH0, accI[0], 0,0,0);
        accR[1] = __builtin_amdgcn_mfma_f32_16x16x32_bf16(aRH,  bRH1, accR[1], 0,0,0);
        accR[1] = __builtin_amdgcn_mfma_f32_16x16x32_bf16(aIHn, bIH1, accR[1], 0,0,0);
        accI[1] = __builtin_amdgcn_mfma_f32_16x16x32_bf16(aRH,  bIH1, accI[1], 0,0,0);
        accI[1] = __builtin_amdgcn_mfma_f32_16x16x32_bf16(aIH,  bRH1, accI[1], 0,0,0);
    }

    // ---- epilogue: D[o][s]; lane holds cols s = tile*16+lr, rows o = g*4+r
    const float2* b2 = (const float2*)b;
    const int obase = o0 + wave*16 + g*4;
    const int hh = obase >> 5, d0 = obase & 31;
    float bR[4], bI[4];
    #pragma unroll
    for (int r = 0; r < 4; ++r) { float2 bb = b2[obase + r]; bR[r] = bb.x; bI[r] = bb.y; }

    if (z == 0) {
        const float osc = 0.2550348677f;   // log2(e)/sqrt(32)
        unsigned short* pr = ws;
        unsigned short* pi = pr + PLANE_U;
        #pragma unroll
        for (int tile = 0; tile < 2; ++tile) {
            int s = s0 + tile*16 + lr;
            size_t idx = ((size_t)hh*S_LEN + s)*HD + d0;
            uint2 pkR, pkI;
            pkR.x = pk_bf16((accR[tile][0]+bR[0])*osc, (accR[tile][1]+bR[1])*osc);
            pkR.y = pk_bf16((accR[tile][2]+bR[2])*osc, (accR[tile][3]+bR[3])*osc);
            pkI.x = pk_bf16((accI[tile][0]+bI[0])*osc, (accI[tile][1]+bI[1])*osc);
            pkI.y = pk_bf16((accI[tile][2]+bI[2])*osc, (accI[tile][3]+bI[3])*osc);
            *(uint2*)&pr[idx] = pkR;
            *(uint2*)&pi[idx] = pkI;
        }
    } else if (z == 1) {
        // KF[h][c][frag][lane][8]: frag by d half; lane = bsel*32 + kappa(key)
        unsigned short* kf = ws + 2*(size_t)PLANE_U;
        const int frag_re = (d0 >= 16) ? 1 : 0;
        const int bsel    = (d0 & 15) >> 3;
        const int e       = d0 & 7;                 // 0 or 4
        #pragma unroll
        for (int tile = 0; tile < 2; ++tile) {
            int s = s0 + tile*16 + lr;              // key
            int c = s >> 5;
            int i = s & 31;
            int r = (i & ~12) | ((i & 4) << 1) | ((i & 8) >> 1);  // kappa
            int lane2 = bsel*32 + r;
            size_t base = ((size_t)(hh*64 + c)*4)*512 + lane2*8 + e;
            uint2 pkR, pkI;
            pkR.x = pk_bf16(accR[tile][0]+bR[0], accR[tile][1]+bR[1]);
            pkR.y = pk_bf16(accR[tile][2]+bR[2], accR[tile][3]+bR[3]);
            pkI.x = pk_bf16(accI[tile][0]+bI[0], accI[tile][1]+bI[1]);
            pkI.y = pk_bf16(accI[tile][2]+bI[2], accI[tile][3]+bI[3]);
            *(uint2*)&kf[base + (size_t)frag_re*512]     = pkR;
            *(uint2*)&kf[base + (size_t)(2+frag_re)*512] = pkI;
        }
    } else {
        // VF[h][c][frag][lane][8]: frag by key half; lane = (lr>>3)*32 + d
        unsigned short* vf = ws + 4*(size_t)PLANE_U;
        const int bsel = lr >> 3;
        const int e    = lr & 7;
        #pragma unroll
        for (int tile = 0; tile < 2; ++tile) {
            int s = s0 + tile*16 + lr;              // key
            const int c       = s >> 5;
            const int frag_re = (s & 31) >= 16 ? 1 : 0;
            const size_t cb   = ((size_t)(hh*64 + c)*4)*512;
            #pragma unroll
            for (int r = 0; r < 4; ++r) {
                int lane2 = bsel*32 + d0 + r;
                size_t base = cb + (size_t)lane2*8 + e;
                vf[base + (size_t)frag_re*512]     =
                    (unsigned short)pk_bf16(accR[tile][r]+bR[r], 0.f);
                vf[base + (size_t)(2+frag_re)*512] =
                    (unsigned short)pk_bf16(accI[tile][r]+bI[r], 0.f);
            }
        }
    }
}

// ---------------- MFMA flash attention (unchanged — passing, ~25us) ------
#define RROW 33

__global__ __launch_bounds__(256, 4)
void attn_mfma(const unsigned short* __restrict__ ws, float* __restrict__ out)
{
    const int bid   = blockIdx.x;       // 64 q-blocks x 16 heads
    const int h     = bid & (NH - 1);
    const int qblk  = bid >> 4;
    const int wave  = threadIdx.x >> 6;
    const int l     = threadIdx.x & 63;
    const int q     = l & 31;
    const int b     = l >> 5;

    const unsigned short* qr = ws + 0*(size_t)PLANE_U + (size_t)h*S_LEN*HD;
    const unsigned short* qi = ws + 1*(size_t)PLANE_U + (size_t)h*S_LEN*HD;
    const unsigned short* kf = ws + 2*(size_t)PLANE_U + ((size_t)h << 17);
    const unsigned short* vf = ws + 4*(size_t)PLANE_U + ((size_t)h << 17);

    const int q0 = qblk * 32;

    bf16x8 bQr_lo = *(const bf16x8*)&qr[(size_t)(q0 + q)*HD + b*8];
    bf16x8 bQr_hi = *(const bf16x8*)&qr[(size_t)(q0 + q)*HD + 16 + b*8];
    bf16x8 bQi_lo = *(const bf16x8*)&qi[(size_t)(q0 + q)*HD + b*8];
    bf16x8 bQi_hi = *(const bf16x8*)&qi[(size_t)(q0 + q)*HD + 16 + b*8];

    __shared__ __align__(16) float2 red[2*32*RROW];

    f32x16 accR, accI;
    #pragma unroll
    for (int r = 0; r < 16; ++r) { accR[r] = 0.f; accI[r] = 0.f; }
    float lsum = 0.f;

    const f32x16 z16 = {0,0,0,0,0,0,0,0,0,0,0,0,0,0,0,0};
    const int kbeg = wave * 512;
    for (int k0 = kbeg; k0 < kbeg + 512; k0 += 32) {
        const size_t fb = (size_t)(k0 >> 5) * 2048 + l*8;

        bf16x8 aVr_lo = *(const bf16x8*)&vf[fb];
        bf16x8 aVr_hi = *(const bf16x8*)&vf[fb + 512];
        bf16x8 aVi_lo = *(const bf16x8*)&vf[fb + 1024];
        bf16x8 aVi_hi = *(const bf16x8*)&vf[fb + 1536];

        bf16x8 aKr_lo = *(const bf16x8*)&kf[fb];
        bf16x8 aKr_hi = *(const bf16x8*)&kf[fb + 512];
        bf16x8 aKi_lo = *(const bf16x8*)&kf[fb + 1024];
        bf16x8 aKi_hi = *(const bf16x8*)&kf[fb + 1536];
        bf16x8 aKin_lo, aKin_hi;
        #pragma unroll
        for (int j = 0; j < 4; ++j) {
            ((unsigned int*)&aKin_lo)[j] = ((const unsigned int*)&aKi_lo)[j] ^ 0x80008000u;
            ((unsigned int*)&aKin_hi)[j] = ((const unsigned int*)&aKi_hi)[j] ^ 0x80008000u;
        }
        f32x16 sR = __builtin_amdgcn_mfma_f32_32x32x16_bf16(aKr_lo,  bQr_lo, z16, 0, 0, 0);
        f32x16 sI = __builtin_amdgcn_mfma_f32_32x32x16_bf16(aKin_lo, bQr_lo, z16, 0, 0, 0);
        sR = __builtin_amdgcn_mfma_f32_32x32x16_bf16(aKr_hi,  bQr_hi, sR, 0, 0, 0);
        sI = __builtin_amdgcn_mfma_f32_32x32x16_bf16(aKin_hi, bQr_hi, sI, 0, 0, 0);
        sR = __builtin_amdgcn_mfma_f32_32x32x16_bf16(aKi_lo,  bQi_lo, sR, 0, 0, 0);
        sI = __builtin_amdgcn_mfma_f32_32x32x16_bf16(aKr_lo,  bQi_lo, sI, 0, 0, 0);
        sR = __builtin_amdgcn_mfma_f32_32x32x16_bf16(aKi_hi,  bQi_hi, sR, 0, 0, 0);
        sI = __builtin_amdgcn_mfma_f32_32x32x16_bf16(aKr_hi,  bQi_hi, sI, 0, 0, 0);

        bf16x8 bP1, bP2;
        unsigned int* p1 = (unsigned int*)&bP1;
        unsigned int* p2 = (unsigned int*)&bP2;
        #pragma unroll
        for (int r2 = 0; r2 < 8; ++r2) {
            int r = 2*r2;
            float v0 = EXP2(__builtin_amdgcn_sqrtf(fmaf(sR[r],   sR[r],   sI[r]*sI[r])));
            float v1 = EXP2(__builtin_amdgcn_sqrtf(fmaf(sR[r+1], sR[r+1], sI[r+1]*sI[r+1])));
            lsum += v0 + v1;
            if (r2 < 4) p1[r2]     = pk_bf16(v0, v1);
            else        p2[r2 - 4] = pk_bf16(v0, v1);
        }
        accR = __builtin_amdgcn_mfma_f32_32x32x16_bf16(aVr_lo, bP1, accR, 0, 0, 0);
        accI = __builtin_amdgcn_mfma_f32_32x32x16_bf16(aVi_lo, bP1, accI, 0, 0, 0);
        accR = __builtin_amdgcn_mfma_f32_32x32x16_bf16(aVr_hi, bP2, accR, 0, 0, 0);
        accI = __builtin_amdgcn_mfma_f32_32x32x16_bf16(aVi_hi, bP2, accI, 0, 0, 0);
    }

    lsum += __shfl_xor(lsum, 32);

    const int rrow = ((wave & 1) * 32 + q) * RROW;
    __syncthreads();
    if (wave < 2) {
        #pragma unroll
        for (int r = 0; r < 16; ++r) {
            int d = (r & 3) + 8*(r >> 2) + 4*b;
            red[rrow + d] = make_float2(accR[r], accI[r]);
        }
        if (b == 0) red[rrow + 32].x = lsum;
    }
    __syncthreads();
    if (wave >= 2) {
        #pragma unroll
        for (int r = 0; r < 16; ++r) {
            int d = (r & 3) + 8*(r >> 2) + 4*b;
            float2 v = red[rrow + d];
            v.x += accR[r]; v.y += accI[r];
            red[rrow + d] = v;
        }
        if (b == 0) red[rrow + 32].x += lsum;
    }
    __syncthreads();

    {
        const int i  = threadIdx.x;
        const int oq = i >> 3;
        const int d0 = (i & 7) * 4;
        float sl = red[oq*RROW + 32].x + red[(32 + oq)*RROW + 32].x;
        float inv = 1.0f / sl;
        float2* o2 = (float2*)out;
        #pragma unroll
        for (int dd = 0; dd < 4; ++dd) {
            int d = d0 + dd;
            float2 v0 = red[oq*RROW + d];
            float2 v1 = red[(32 + oq)*RROW + d];
            o2[(size_t)(q0 + oq)*C_DIM + h*HD + d] =
                make_float2((v0.x + v1.x)*inv, (v0.y + v1.y)*inv);
        }
    }
}

extern "C" void kernel_launch(void* const* d_in, const int* in_sizes, int n_in,
                              void* d_out, int out_size, void* d_ws, size_t ws_size,
                              hipStream_t stream)
{
    const float* Q  = (const float*)d_in[0];
    const float* V  = (const float*)d_in[1];
    const float* K  = (const float*)d_in[2];
    const float* Wq = (const float*)d_in[3];
    const float* bq = (const float*)d_in[4];
    const float* Wk = (const float*)d_in[5];
    const float* bk = (const float*)d_in[6];
    const float* Wv = (const float*)d_in[7];
    const float* bv = (const float*)d_in[8];
    unsigned short* ws = (unsigned short*)d_ws;   // 12MB planes + 12MB XF + 3MB WF = 27MB
    float* out = (float*)d_out;

    xcvt<<<1536, 256, 0, stream>>>(Q, K, V, ws);
    wcvt<<<384, 256, 0, stream>>>(Wq, Wk, Wv, ws);
    proj_mfma<<<dim3(S_LEN/32, C_DIM/64, 3), 256, 0, stream>>>(bq, bk, bv, ws);
    attn_mfma<<<dim3(64*NH), 256, 0, stream>>>(ws, out);
}

// Round 22
// 72.727 us; speedup vs baseline: 1.3508x; 1.0754x over previous
//
#include <hip/hip_runtime.h>
#include <hip/hip_bf16.h>
#include <math.h>

#define S_LEN 2048
#define C_DIM 512
#define NH 16
#define HD 32
#define PLANE_U (NH * S_LEN * HD)   // 1,048,576 ushorts = 2MB per plane
#define XF_OFF  (6*(size_t)PLANE_U)   // X fragment planes: 3z x {re,im} x 2MB
#define WF_OFF  (12*(size_t)PLANE_U)  // W fragment planes: 3z x {re,im} x 512KB
#define WPLF 262144                   // 512*512 ushorts per W plane

typedef __attribute__((ext_vector_type(8)))  short bf16x8;
typedef __attribute__((ext_vector_type(4)))  float f32x4;
typedef __attribute__((ext_vector_type(16))) float f32x16;
typedef __attribute__((ext_vector_type(4)))  unsigned int u32x4;

#if __has_builtin(__builtin_amdgcn_exp2f)
#define EXP2(x) __builtin_amdgcn_exp2f(x)
#else
#define EXP2(x) exp2f(x)
#endif

// pack 2 floats -> 2 bf16 in one dword via v_cvt_pk_bf16_f32 (RNE); a = low
__device__ __forceinline__ unsigned int pk_bf16(float a, float b) {
    float2 f; f.x = a; f.y = b;
    __hip_bfloat162 t = __float22bfloat162_rn(f);
    return *reinterpret_cast<unsigned int*>(&t);
}

// ---------------- fused X+W pre-conversion to fragment-order bf16 --------
// blocks [0,1536):  XF[z][{re,im}][sb:128][kc:16][lane:64][e:8]
//                   (lane = g*16+lr holds X[s=sb*16+lr][k=kc*32+g*8+e])
// blocks [1536,1920): WFB[z][{re,im}][ob:32][kc:16][lane:64][e:8]
__global__ __launch_bounds__(256)
void xwcvt(const float* __restrict__ Q, const float* __restrict__ K,
           const float* __restrict__ V,
           const float* __restrict__ Wq, const float* __restrict__ Wk,
           const float* __restrict__ Wv, unsigned short* __restrict__ ws)
{
    if (blockIdx.x < 1536) {
        const int tid  = blockIdx.x*256 + threadIdx.x;   // 393,216
        const int z    = tid >> 17;
        const int rem  = tid & 131071;
        const int kidx = rem >> 11;          // 0..63 (k-chunk of 8)
        const int s    = rem & 2047;
        const int k    = kidx * 8;
        const float2* x2 = (const float2*)(z == 0 ? Q : (z == 1 ? K : V));
        const float4* s4 = (const float4*)(x2 + (size_t)s*C_DIM + k);
        float4 f0 = s4[0], f1 = s4[1], f2v = s4[2], f3 = s4[3];
        u32x4 rh, ih;
        rh[0] = pk_bf16(f0.x, f0.z); rh[1] = pk_bf16(f1.x, f1.z);
        rh[2] = pk_bf16(f2v.x, f2v.z); rh[3] = pk_bf16(f3.x, f3.z);
        ih[0] = pk_bf16(f0.y, f0.w); ih[1] = pk_bf16(f1.y, f1.w);
        ih[2] = pk_bf16(f2v.y, f2v.w); ih[3] = pk_bf16(f3.y, f3.w);
        const int sb = s >> 4, lr = s & 15, g = kidx & 3, kc = kidx >> 2;
        const size_t off = ((size_t)(sb*16 + kc)*64 + g*16 + lr)*8;
        unsigned short* base = ws + XF_OFF + (size_t)z*2*PLANE_U;
        *(u32x4*)&base[off]           = rh;
        *(u32x4*)&base[PLANE_U + off] = ih;
    } else {
        const int tid  = (blockIdx.x - 1536)*256 + threadIdx.x;  // 98,304
        const int z    = tid >> 15;
        const int rem  = tid & 32767;
        const int kidx = rem >> 9;           // 0..63
        const int o    = rem & 511;
        const int k    = kidx * 8;
        const float2* w2 = (const float2*)(z == 0 ? Wq : (z == 1 ? Wk : Wv));
        const float4* s4 = (const float4*)(w2 + (size_t)o*C_DIM + k);
        float4 f0 = s4[0], f1 = s4[1], f2v = s4[2], f3 = s4[3];
        u32x4 rh, ih;
        rh[0] = pk_bf16(f0.x, f0.z); rh[1] = pk_bf16(f1.x, f1.z);
        rh[2] = pk_bf16(f2v.x, f2v.z); rh[3] = pk_bf16(f3.x, f3.z);
        ih[0] = pk_bf16(f0.y, f0.w); ih[1] = pk_bf16(f1.y, f1.w);
        ih[2] = pk_bf16(f2v.y, f2v.w); ih[3] = pk_bf16(f3.y, f3.w);
        const int ob = o >> 4, lr = o & 15, g = kidx & 3, kc = kidx >> 2;
        const size_t off = ((size_t)(ob*16 + kc)*64 + g*16 + lr)*8;
        unsigned short* base = ws + WF_OFF + (size_t)z*2*WPLF;
        *(u32x4*)&base[off]        = rh;
        *(u32x4*)&base[WPLF + off] = ih;
    }
}

// ---------------- projection: barrier-free complex GEMM ------------------
// D = W·X^T, hi-only RNE. NO LDS, NO __syncthreads: both operands load as
// contiguous 1KB wave-fragments from the pre-converted XF/WFB planes.
// Wave = 16 o-rows x 32 s-cols; grid 64(s) x 8(o) x 3(z) = 1536 blocks.
// A fragment for kc+1 is hoisted above kc's MFMA block (free-running waves,
// no barrier to defeat the prefetch this time).
// z==0 (q): -> natural [h][s][d], PRE-SCALED by log2(e)/sqrt(32)
// z==1 (k): -> fragment-order KF[h][c][frag][lane][8], kappa pre-folded
// z==2 (v): -> fragment-order VF[h][c][frag][lane][8] (from D[o][s])
__global__ __launch_bounds__(256)
void proj_mfma(const float* __restrict__ bq, const float* __restrict__ bk,
               const float* __restrict__ bv,
               unsigned short* __restrict__ ws)
{
    const int z = blockIdx.z;
    const float* b = (z == 0) ? bq : (z == 1 ? bk : bv);

    const int s0 = blockIdx.x * 32;
    const int o0 = blockIdx.y * 64;

    const unsigned short* xfR = ws + XF_OFF + (size_t)z*2*PLANE_U;
    const unsigned short* xfI = xfR + PLANE_U;
    const unsigned short* wfR = ws + WF_OFF + (size_t)z*2*WPLF;
    const unsigned short* wfI = wfR + WPLF;

    const int t    = threadIdx.x;
    const int wave = t >> 6;
    const int lane = t & 63;
    const int lr   = t & 15;
    const int g    = (t & 63) >> 4;

    const int ob = (o0 >> 4) + wave;    // W row-block
    const int sb = s0 >> 4;             // X row-blocks sb, sb+1

    const f32x4 zf = {0.f,0.f,0.f,0.f};
    f32x4 accR[2], accI[2];
    #pragma unroll
    for (int i = 0; i < 2; ++i) { accR[i] = zf; accI[i] = zf; }

    size_t aoff = ((size_t)(ob*16)*64 + lane)*8;
    bf16x8 aRH = *(const bf16x8*)&wfR[aoff];
    bf16x8 aIH = *(const bf16x8*)&wfI[aoff];

    #pragma unroll
    for (int kc = 0; kc < 16; ++kc) {
        bf16x8 aIHn;
        #pragma unroll
        for (int j = 0; j < 4; ++j)
            ((unsigned int*)&aIHn)[j] = ((const unsigned int*)&aIH)[j] ^ 0x80008000u;

        const size_t b0 = ((size_t)(sb*16 + kc)*64 + lane)*8;
        const size_t b1 = ((size_t)((sb+1)*16 + kc)*64 + lane)*8;
        bf16x8 bRH0 = *(const bf16x8*)&xfR[b0];
        bf16x8 bIH0 = *(const bf16x8*)&xfI[b0];
        bf16x8 bRH1 = *(const bf16x8*)&xfR[b1];
        bf16x8 bIH1 = *(const bf16x8*)&xfI[b1];

        bf16x8 aRHc = aRH, aIHc = aIH;
        if (kc < 15) {                   // prefetch next A (L2-hot W)
            const size_t an = ((size_t)(ob*16 + kc + 1)*64 + lane)*8;
            aRH = *(const bf16x8*)&wfR[an];
            aIH = *(const bf16x8*)&wfI[an];
        }

        accR[0] = __builtin_amdgcn_mfma_f32_16x16x32_bf16(aRHc, bRH0, accR[0], 0,0,0);
        accR[0] = __builtin_amdgcn_mfma_f32_16x16x32_bf16(aIHn, bIH0, accR[0], 0,0,0);
        accI[0] = __builtin_amdgcn_mfma_f32_16x16x32_bf16(aRHc, bIH0, accI[0], 0,0,0);
        accI[0] = __builtin_amdgcn_mfma_f32_16x16x32_bf16(aIHc, bRH0, accI[0], 0,0,0);
        accR[1] = __builtin_amdgcn_mfma_f32_16x16x32_bf16(aRHc, bRH1, accR[1], 0,0,0);
        accR[1] = __builtin_amdgcn_mfma_f32_16x16x32_bf16(aIHn, bIH1, accR[1], 0,0,0);
        accI[1] = __builtin_amdgcn_mfma_f32_16x16x32_bf16(aRHc, bIH1, accI[1], 0,0,0);
        accI[1] = __builtin_amdgcn_mfma_f32_16x16x32_bf16(aIHc, bRH1, accI[1], 0,0,0);
    }

    // ---- epilogue: D[o][s]; lane holds cols s = tile*16+lr, rows o = g*4+r
    const float2* b2 = (const float2*)b;
    const int obase = o0 + wave*16 + g*4;
    const int hh = obase >> 5, d0 = obase & 31;
    float bR[4], bI[4];
    #pragma unroll
    for (int r = 0; r < 4; ++r) { float2 bb = b2[obase + r]; bR[r] = bb.x; bI[r] = bb.y; }

    if (z == 0) {
        const float osc = 0.2550348677f;   // log2(e)/sqrt(32)
        unsigned short* pr = ws;
        unsigned short* pi = pr + PLANE_U;
        #pragma unroll
        for (int tile = 0; tile < 2; ++tile) {
            int s = s0 + tile*16 + lr;
            size_t idx = ((size_t)hh*S_LEN + s)*HD + d0;
            uint2 pkR, pkI;
            pkR.x = pk_bf16((accR[tile][0]+bR[0])*osc, (accR[tile][1]+bR[1])*osc);
            pkR.y = pk_bf16((accR[tile][2]+bR[2])*osc, (accR[tile][3]+bR[3])*osc);
            pkI.x = pk_bf16((accI[tile][0]+bI[0])*osc, (accI[tile][1]+bI[1])*osc);
            pkI.y = pk_bf16((accI[tile][2]+bI[2])*osc, (accI[tile][3]+bI[3])*osc);
            *(uint2*)&pr[idx] = pkR;
            *(uint2*)&pi[idx] = pkI;
        }
    } else if (z == 1) {
        // KF[h][c][frag][lane][8]: frag by d half; lane = bsel*32 + kappa(key)
        unsigned short* kf = ws + 2*(size_t)PLANE_U;
        const int frag_re = (d0 >= 16) ? 1 : 0;
        const int bsel    = (d0 & 15) >> 3;
        const int e       = d0 & 7;                 // 0 or 4
        #pragma unroll
        for (int tile = 0; tile < 2; ++tile) {
            int s = s0 + tile*16 + lr;              // key
            int c = s >> 5;
            int i = s & 31;
            int r = (i & ~12) | ((i & 4) << 1) | ((i & 8) >> 1);  // kappa
            int lane2 = bsel*32 + r;
            size_t base = ((size_t)(hh*64 + c)*4)*512 + lane2*8 + e;
            uint2 pkR, pkI;
            pkR.x = pk_bf16(accR[tile][0]+bR[0], accR[tile][1]+bR[1]);
            pkR.y = pk_bf16(accR[tile][2]+bR[2], accR[tile][3]+bR[3]);
            pkI.x = pk_bf16(accI[tile][0]+bI[0], accI[tile][1]+bI[1]);
            pkI.y = pk_bf16(accI[tile][2]+bI[2], accI[tile][3]+bI[3]);
            *(uint2*)&kf[base + (size_t)frag_re*512]     = pkR;
            *(uint2*)&kf[base + (size_t)(2+frag_re)*512] = pkI;
        }
    } else {
        // VF[h][c][frag][lane][8]: frag by key half; lane = (lr>>3)*32 + d
        unsigned short* vf = ws + 4*(size_t)PLANE_U;
        const int bsel = lr >> 3;
        const int e    = lr & 7;
        #pragma unroll
        for (int tile = 0; tile < 2; ++tile) {
            int s = s0 + tile*16 + lr;              // key
            const int c       = s >> 5;
            const int frag_re = (s & 31) >= 16 ? 1 : 0;
            const size_t cb   = ((size_t)(hh*64 + c)*4)*512;
            #pragma unroll
            for (int r = 0; r < 4; ++r) {
                int lane2 = bsel*32 + d0 + r;
                size_t base = cb + (size_t)lane2*8 + e;
                vf[base + (size_t)frag_re*512]     =
                    (unsigned short)pk_bf16(accR[tile][r]+bR[r], 0.f);
                vf[base + (size_t)(2+frag_re)*512] =
                    (unsigned short)pk_bf16(accI[tile][r]+bI[r], 0.f);
            }
        }
    }
}

// ---------------- MFMA flash attention + s_setprio (independent waves) ---
#define RROW 33

__global__ __launch_bounds__(256, 4)
void attn_mfma(const unsigned short* __restrict__ ws, float* __restrict__ out)
{
    const int bid   = blockIdx.x;       // 64 q-blocks x 16 heads
    const int h     = bid & (NH - 1);
    const int qblk  = bid >> 4;
    const int wave  = threadIdx.x >> 6;
    const int l     = threadIdx.x & 63;
    const int q     = l & 31;
    const int b     = l >> 5;

    const unsigned short* qr = ws + 0*(size_t)PLANE_U + (size_t)h*S_LEN*HD;
    const unsigned short* qi = ws + 1*(size_t)PLANE_U + (size_t)h*S_LEN*HD;
    const unsigned short* kf = ws + 2*(size_t)PLANE_U + ((size_t)h << 17);
    const unsigned short* vf = ws + 4*(size_t)PLANE_U + ((size_t)h << 17);

    const int q0 = qblk * 32;

    bf16x8 bQr_lo = *(const bf16x8*)&qr[(size_t)(q0 + q)*HD + b*8];
    bf16x8 bQr_hi = *(const bf16x8*)&qr[(size_t)(q0 + q)*HD + 16 + b*8];
    bf16x8 bQi_lo = *(const bf16x8*)&qi[(size_t)(q0 + q)*HD + b*8];
    bf16x8 bQi_hi = *(const bf16x8*)&qi[(size_t)(q0 + q)*HD + 16 + b*8];

    __shared__ __align__(16) float2 red[2*32*RROW];

    f32x16 accR, accI;
    #pragma unroll
    for (int r = 0; r < 16; ++r) { accR[r] = 0.f; accI[r] = 0.f; }
    float lsum = 0.f;

    const f32x16 z16 = {0,0,0,0,0,0,0,0,0,0,0,0,0,0,0,0};
    const int kbeg = wave * 512;
    for (int k0 = kbeg; k0 < kbeg + 512; k0 += 32) {
        const size_t fb = (size_t)(k0 >> 5) * 2048 + l*8;

        bf16x8 aVr_lo = *(const bf16x8*)&vf[fb];
        bf16x8 aVr_hi = *(const bf16x8*)&vf[fb + 512];
        bf16x8 aVi_lo = *(const bf16x8*)&vf[fb + 1024];
        bf16x8 aVi_hi = *(const bf16x8*)&vf[fb + 1536];

        bf16x8 aKr_lo = *(const bf16x8*)&kf[fb];
        bf16x8 aKr_hi = *(const bf16x8*)&kf[fb + 512];
        bf16x8 aKi_lo = *(const bf16x8*)&kf[fb + 1024];
        bf16x8 aKi_hi = *(const bf16x8*)&kf[fb + 1536];
        bf16x8 aKin_lo, aKin_hi;
        #pragma unroll
        for (int j = 0; j < 4; ++j) {
            ((unsigned int*)&aKin_lo)[j] = ((const unsigned int*)&aKi_lo)[j] ^ 0x80008000u;
            ((unsigned int*)&aKin_hi)[j] = ((const unsigned int*)&aKi_hi)[j] ^ 0x80008000u;
        }
        __builtin_amdgcn_s_setprio(1);
        f32x16 sR = __builtin_amdgcn_mfma_f32_32x32x16_bf16(aKr_lo,  bQr_lo, z16, 0, 0, 0);
        f32x16 sI = __builtin_amdgcn_mfma_f32_32x32x16_bf16(aKin_lo, bQr_lo, z16, 0, 0, 0);
        sR = __builtin_amdgcn_mfma_f32_32x32x16_bf16(aKr_hi,  bQr_hi, sR, 0, 0, 0);
        sI = __builtin_amdgcn_mfma_f32_32x32x16_bf16(aKin_hi, bQr_hi, sI, 0, 0, 0);
        sR = __builtin_amdgcn_mfma_f32_32x32x16_bf16(aKi_lo,  bQi_lo, sR, 0, 0, 0);
        sI = __builtin_amdgcn_mfma_f32_32x32x16_bf16(aKr_lo,  bQi_lo, sI, 0, 0, 0);
        sR = __builtin_amdgcn_mfma_f32_32x32x16_bf16(aKi_hi,  bQi_hi, sR, 0, 0, 0);
        sI = __builtin_amdgcn_mfma_f32_32x32x16_bf16(aKr_hi,  bQi_hi, sI, 0, 0, 0);
        __builtin_amdgcn_s_setprio(0);

        bf16x8 bP1, bP2;
        unsigned int* p1 = (unsigned int*)&bP1;
        unsigned int* p2 = (unsigned int*)&bP2;
        #pragma unroll
        for (int r2 = 0; r2 < 8; ++r2) {
            int r = 2*r2;
            float v0 = EXP2(__builtin_amdgcn_sqrtf(fmaf(sR[r],   sR[r],   sI[r]*sI[r])));
            float v1 = EXP2(__builtin_amdgcn_sqrtf(fmaf(sR[r+1], sR[r+1], sI[r+1]*sI[r+1])));
            lsum += v0 + v1;
            if (r2 < 4) p1[r2]     = pk_bf16(v0, v1);
            else        p2[r2 - 4] = pk_bf16(v0, v1);
        }
        __builtin_amdgcn_s_setprio(1);
        accR = __builtin_amdgcn_mfma_f32_32x32x16_bf16(aVr_lo, bP1, accR, 0, 0, 0);
        accI = __builtin_amdgcn_mfma_f32_32x32x16_bf16(aVi_lo, bP1, accI, 0, 0, 0);
        accR = __builtin_amdgcn_mfma_f32_32x32x16_bf16(aVr_hi, bP2, accR, 0, 0, 0);
        accI = __builtin_amdgcn_mfma_f32_32x32x16_bf16(aVi_hi, bP2, accI, 0, 0, 0);
        __builtin_amdgcn_s_setprio(0);
    }

    lsum += __shfl_xor(lsum, 32);

    const int rrow = ((wave & 1) * 32 + q) * RROW;
    __syncthreads();
    if (wave < 2) {
        #pragma unroll
        for (int r = 0; r < 16; ++r) {
            int d = (r & 3) + 8*(r >> 2) + 4*b;
            red[rrow + d] = make_float2(accR[r], accI[r]);
        }
        if (b == 0) red[rrow + 32].x = lsum;
    }
    __syncthreads();
    if (wave >= 2) {
        #pragma unroll
        for (int r = 0; r < 16; ++r) {
            int d = (r & 3) + 8*(r >> 2) + 4*b;
            float2 v = red[rrow + d];
            v.x += accR[r]; v.y += accI[r];
            red[rrow + d] = v;
        }
        if (b == 0) red[rrow + 32].x += lsum;
    }
    __syncthreads();

    {
        const int i  = threadIdx.x;
        const int oq = i >> 3;
        const int d0 = (i & 7) * 4;
        float sl = red[oq*RROW + 32].x + red[(32 + oq)*RROW + 32].x;
        float inv = 1.0f / sl;
        float2* o2 = (float2*)out;
        #pragma unroll
        for (int dd = 0; dd < 4; ++dd) {
            int d = d0 + dd;
            float2 v0 = red[oq*RROW + d];
            float2 v1 = red[(32 + oq)*RROW + d];
            o2[(size_t)(q0 + oq)*C_DIM + h*HD + d] =
                make_float2((v0.x + v1.x)*inv, (v0.y + v1.y)*inv);
        }
    }
}

extern "C" void kernel_launch(void* const* d_in, const int* in_sizes, int n_in,
                              void* d_out, int out_size, void* d_ws, size_t ws_size,
                              hipStream_t stream)
{
    const float* Q  = (const float*)d_in[0];
    const float* V  = (const float*)d_in[1];
    const float* K  = (const float*)d_in[2];
    const float* Wq = (const float*)d_in[3];
    const float* bq = (const float*)d_in[4];
    const float* Wk = (const float*)d_in[5];
    const float* bk = (const float*)d_in[6];
    const float* Wv = (const float*)d_in[7];
    const float* bv = (const float*)d_in[8];
    unsigned short* ws = (unsigned short*)d_ws;   // 12MB planes + 12MB XF + 3MB WF = 27MB
    float* out = (float*)d_out;

    xwcvt<<<1920, 256, 0, stream>>>(Q, K, V, Wq, Wk, Wv, ws);
    proj_mfma<<<dim3(S_LEN/32, C_DIM/64, 3), 256, 0, stream>>>(bq, bk, bv, ws);
    attn_mfma<<<dim3(64*NH), 256, 0, stream>>>(ws, out);
}